// Round 7
// baseline (121.108 us; speedup 1.0000x reference)
//
#include <hip/hip_runtime.h>
#include <hip/hip_bf16.h>

// Quanvolution classifier, round 7: SINGLE-DISPATCH mega-fusion.
// One block = one sample. Each block:
//   phase 1: rebuild the folded coefficient table C (40x16, padded) in LDS
//            from vparams (redundant per block; ~1-2 us, concurrent).
//   phase 2: thread p<196 computes patch p's <Z_w> via the quadratic form
//            e_w = sum_{a,b} C_w[a][b] P_a Q_b   (C broadcast from LDS).
//   phase 3: per-thread dot with W rows, 64-lane butterfly + 4-wave LDS
//            fold, thread 0 does log-softmax and writes 10 outputs.
// No workspace traffic at all (d_ws unused).
//
// Algebra (validated rounds 1-6): variational circuit is data-independent =>
// U (16x16 complex) fixed; encoder state s = p (x) q real product state;
// e_w = s^T M_w s, M_w = Re(U^dag Z_w U), folded over unique index pairs.
// Wire convention: wire 0 = MSB; i = 4*jp + jq, s[i] = p[jp]*q[jq],
// p = (c0c1, c0s1, s0c1, s0s1), q = (c2c3, c2s3, s2c3, s2s3).

#define NPATCH 196

__global__ __launch_bounds__(256) void qc_all(const float* __restrict__ x,
                                              const float* __restrict__ vp,
                                              const float4* __restrict__ W4,
                                              const float* __restrict__ bias,
                                              float* __restrict__ out) {
  __shared__ float Ur[16][16];   // [i][j]
  __shared__ float Ui[16][16];
  __shared__ float M[4][16][16];
  __shared__ float4 sC[160];     // 40 rows x 4 float4, cols 10..15 zero
  __shared__ float red[4][10];

  const int t = threadIdx.x;
  const int b = blockIdx.x;

  // ---------------- phase 1: build C in LDS ------------------------------
  if (t < 16) {
    float sr[16], si[16];
#pragma unroll
    for (int i = 0; i < 16; ++i) { sr[i] = 0.f; si[i] = 0.f; }
    sr[t] = 1.f;

    for (int l = 0; l < 3; ++l) {
#pragma unroll
      for (int w = 0; w < 4; ++w) {
        float thy = vp[l * 8 + (w % 8)];
        float thz = vp[l * 8 + ((w + 1) % 8)];
        float cy, sy, cz, sz;
        __sincosf(0.5f * thy, &sy, &cy);
        __sincosf(0.5f * thz, &sz, &cz);
        const int bit = 8 >> w;
        // RY
#pragma unroll
        for (int i = 0; i < 16; ++i) {
          if (!(i & bit)) {
            int i1 = i | bit;
            float a0r = sr[i], a0i = si[i], a1r = sr[i1], a1i = si[i1];
            sr[i]  = cy * a0r - sy * a1r;  si[i]  = cy * a0i - sy * a1i;
            sr[i1] = sy * a0r + cy * a1r;  si[i1] = sy * a0i + cy * a1i;
          }
        }
        // RZ: amp0 *= e^{-i thz/2}, amp1 *= e^{+i thz/2}
#pragma unroll
        for (int i = 0; i < 16; ++i) {
          float r = sr[i], m = si[i];
          if (i & bit) { sr[i] = r * cz - m * sz; si[i] = m * cz + r * sz; }
          else         { sr[i] = r * cz + m * sz; si[i] = m * cz - r * sz; }
        }
      }
      // CX ring
#pragma unroll
      for (int w = 0; w < 4; ++w) {
        const int cbit = 8 >> w;
        const int tbit = 8 >> ((w + 1) & 3);
#pragma unroll
        for (int i = 0; i < 16; ++i) {
          if ((i & cbit) && !(i & tbit)) {
            int i1 = i | tbit;
            float tr = sr[i], ti = si[i];
            sr[i] = sr[i1]; si[i] = si[i1];
            sr[i1] = tr;    si[i1] = ti;
          }
        }
      }
    }
#pragma unroll
    for (int i = 0; i < 16; ++i) { Ur[i][t] = sr[i]; Ui[i][t] = si[i]; }
  }
  __syncthreads();

  // M_w[r][c] = sum_i sgn_w(i) * (Ur[i][r]Ur[i][c] + Ui[i][r]Ui[i][c])
#pragma unroll
  for (int e = t; e < 1024; e += 256) {
    int w = e >> 8, r = (e >> 4) & 15, c = e & 15;
    float acc = 0.f;
#pragma unroll
    for (int i = 0; i < 16; ++i) {
      float sgn = ((i >> (3 - w)) & 1) ? -1.f : 1.f;
      acc += sgn * (Ur[i][r] * Ur[i][c] + Ui[i][r] * Ui[i][c]);
    }
    M[w][r][c] = acc;
  }
  __syncthreads();

  {
    const int pj1[10] = {0, 0, 0, 0, 1, 1, 1, 2, 2, 3};
    const int pj2[10] = {0, 1, 2, 3, 1, 2, 3, 2, 3, 3};
    float* sCf = (float*)sC;
    for (int e = t; e < 640; e += 256) {
      int row = e >> 4;          // w*10 + a
      int col = e & 15;          // b (or pad)
      float v = 0.f;
      if (col < 10) {
        int w = row / 10;
        int a = row - w * 10;
        int j1 = pj1[a], j2 = pj2[a], k1 = pj1[col], k2 = pj2[col];
        v = M[w][4 * j1 + k1][4 * j2 + k2];
        if (k1 != k2) v += M[w][4 * j1 + k2][4 * j2 + k1];
        if (j1 != j2) {
          v += M[w][4 * j2 + k1][4 * j1 + k2];
          if (k1 != k2) v += M[w][4 * j2 + k2][4 * j1 + k1];
        }
      }
      sCf[e] = v;
    }
  }
  __syncthreads();

  // ---------------- phase 2+3: patch quadratic form + head ---------------
  float lg[10];
#pragma unroll
  for (int c = 0; c < 10; ++c) lg[c] = 0.f;

  if (t < NPATCH) {
    int pr = t / 14;
    int pc = t - pr * 14;
    const float* xb = x + (size_t)b * 784;
    float2 top = *(const float2*)(xb + 56 * pr + 2 * pc);
    float2 bot = *(const float2*)(xb + 56 * pr + 28 + 2 * pc);

    float s0, c0, s1, c1, s2, c2, s3, c3;
    __sincosf(0.5f * top.x, &s0, &c0);
    __sincosf(0.5f * top.y, &s1, &c1);
    __sincosf(0.5f * bot.x, &s2, &c2);
    __sincosf(0.5f * bot.y, &s3, &c3);

    float p0 = c0 * c1, p1 = c0 * s1, p2 = s0 * c1, p3 = s0 * s1;
    float q0 = c2 * c3, q1 = c2 * s3, q2 = s2 * c3, q3 = s2 * s3;

    float P[10] = {p0 * p0, p0 * p1, p0 * p2, p0 * p3, p1 * p1,
                   p1 * p2, p1 * p3, p2 * p2, p2 * p3, p3 * p3};
    float Q[10] = {q0 * q0, q0 * q1, q0 * q2, q0 * q3, q1 * q1,
                   q1 * q2, q1 * q3, q2 * q2, q2 * q3, q3 * q3};

    float e[4];
#pragma unroll
    for (int w = 0; w < 4; ++w) {
      float acc = 0.f;
#pragma unroll
      for (int a = 0; a < 10; ++a) {
        int base = (w * 10 + a) * 4;   // constant per unrolled iteration
        float4 r0 = sC[base];
        float4 r1 = sC[base + 1];
        float4 r2 = sC[base + 2];      // .z,.w are 0-pad
        float tt = r0.x * Q[0] + r0.y * Q[1] + r0.z * Q[2] + r0.w * Q[3]
                 + r1.x * Q[4] + r1.y * Q[5] + r1.z * Q[6] + r1.w * Q[7]
                 + r2.x * Q[8] + r2.y * Q[9];
        acc += P[a] * tt;
      }
      e[w] = acc;
    }

    float4 f = make_float4(e[0], e[1], e[2], e[3]);
#pragma unroll
    for (int c = 0; c < 10; ++c) {
      float4 w = W4[c * NPATCH + t];
      lg[c] = f.x * w.x + f.y * w.y + f.z * w.z + f.w * w.w;
    }
  }

  // 64-lane butterfly per wave
#pragma unroll
  for (int off = 32; off >= 1; off >>= 1)
#pragma unroll
    for (int c = 0; c < 10; ++c)
      lg[c] += __shfl_xor(lg[c], off, 64);

  int wave = t >> 6;
  int lane = t & 63;
  if (lane == 0) {
#pragma unroll
    for (int c = 0; c < 10; ++c) red[wave][c] = lg[c];
  }
  __syncthreads();

  if (t == 0) {
    float L[10], m = -1e30f;
#pragma unroll
    for (int c = 0; c < 10; ++c) {
      L[c] = red[0][c] + red[1][c] + red[2][c] + red[3][c] + bias[c];
      m = fmaxf(m, L[c]);
    }
    float ssum = 0.f;
#pragma unroll
    for (int c = 0; c < 10; ++c) ssum += __expf(L[c] - m);
    float ls = m + __logf(ssum);
#pragma unroll
    for (int c = 0; c < 10; ++c) out[b * 10 + c] = L[c] - ls;
  }
}

extern "C" void kernel_launch(void* const* d_in, const int* in_sizes, int n_in,
                              void* d_out, int out_size, void* d_ws, size_t ws_size,
                              hipStream_t stream) {
  const float* x    = (const float*)d_in[0];  // (B,1,28,28)
  const float* vp   = (const float*)d_in[1];  // (3,8)
  const float* W    = (const float*)d_in[2];  // (10,784)
  const float* bias = (const float*)d_in[3];  // (10,)
  float* out = (float*)d_out;

  int B = in_sizes[0] / 784;

  qc_all<<<B, 256, 0, stream>>>(x, vp, (const float4*)W, bias, out);
}